// Round 4
// baseline (2161.989 us; speedup 1.0000x reference)
//
#include <hip/hip_runtime.h>

typedef __attribute__((ext_vector_type(4))) float f32x4;
typedef __attribute__((ext_vector_type(8))) short bf16x8;

#define B_   128
#define T_   1024
#define NROW 131072      // B*T
#define HB   (NROW*300)  // floats in the [B*T][300] matrix

__device__ inline unsigned short f2bf(float f) {
    union { float f; unsigned int u; } v; v.f = f;
    unsigned int r = v.u + 0x7FFFu + ((v.u >> 16) & 1u);
    return (unsigned short)(r >> 16);
}

// Load up to 8 consecutive f32 (zero-masked at K=300 boundary), convert to bf16,
// return packed uint4 (8 bf16, fragment j-order = ascending k).
__device__ inline uint4 load8_cvt(const float* src, bool rowok, int krem) {
    f32x4 v0 = {0.f,0.f,0.f,0.f}, v1 = {0.f,0.f,0.f,0.f};
    if (rowok) {
        if (krem >= 8)      { v0 = *(const f32x4*)src; v1 = *(const f32x4*)(src + 4); }
        else if (krem >= 4) { v0 = *(const f32x4*)src; }
    }
    uint4 p;
    p.x = (unsigned)f2bf(v0[0]) | ((unsigned)f2bf(v0[1]) << 16);
    p.y = (unsigned)f2bf(v0[2]) | ((unsigned)f2bf(v0[3]) << 16);
    p.z = (unsigned)f2bf(v1[0]) | ((unsigned)f2bf(v1[1]) << 16);
    p.w = (unsigned)f2bf(v1[2]) | ((unsigned)f2bf(v1[3]) << 16);
    return p;
}

// ---------------------------------------------------------------------------
// K1: A[m][n] = sum_k X[m][k]*W1[n][k] + b1[n]   (bf16 MFMA, f32 out)
// Block: 256 thr (4 waves), BM=128 (8 M-tiles, 2/wave), BN=160 (10 N-tiles),
// K padded 300->320, BK=32. Grid (1024, 2).
// ---------------------------------------------------------------------------
__global__ __launch_bounds__(256) void gemm_in(
    const float* __restrict__ X, const float* __restrict__ W1,
    const float* __restrict__ b1, float* __restrict__ A)
{
    __shared__ unsigned short alds[8 * 64 * 8];    // frag-linear x tile
    __shared__ unsigned short blds[10 * 64 * 8];   // frag-linear W tile
    const int tid = threadIdx.x;
    const int w = tid >> 6, l = tid & 63, lg = l >> 4, ln = l & 15;
    const size_t m0 = (size_t)blockIdx.x * 128;
    const int n0 = blockIdx.y * 160;

    f32x4 acc[2][10];
    #pragma unroll
    for (int q = 0; q < 2; ++q)
        #pragma unroll
        for (int nt = 0; nt < 10; ++nt) acc[q][nt] = (f32x4){0.f,0.f,0.f,0.f};

    for (int kt = 0; kt < 10; ++kt) {
        const int kc = kt * 32;
        __syncthreads();
        // stage X tile: 128 rows x 32 k -> frag-linear
        #pragma unroll
        for (int rep = 0; rep < 2; ++rep) {
            int e = tid + rep * 256;            // < 512
            int row = e >> 2, kh = e & 3;
            int k0 = kc + kh * 8;
            uint4 p = load8_cvt(X + (m0 + row) * 300 + k0, true, 300 - k0);
            *(uint4*)&alds[(((row >> 4) * 64) + kh * 16 + (row & 15)) * 8] = p;
        }
        // stage W tile: 160 n-rows x 32 k
        #pragma unroll
        for (int rep = 0; rep < 3; ++rep) {
            int e = tid + rep * 256;
            if (e < 640) {
                int nn = e >> 2, kh = e & 3;
                int n = n0 + nn;
                int k0 = kc + kh * 8;
                uint4 p = load8_cvt(W1 + (size_t)n * 600 + k0, n < 300, 300 - k0);
                *(uint4*)&blds[(((nn >> 4) * 64) + kh * 16 + (nn & 15)) * 8] = p;
            }
        }
        __syncthreads();
        bf16x8 bfr[10];
        #pragma unroll
        for (int nt = 0; nt < 10; ++nt) bfr[nt] = *(const bf16x8*)&blds[(nt * 64 + l) * 8];
        #pragma unroll
        for (int q = 0; q < 2; ++q) {
            bf16x8 afr = *(const bf16x8*)&alds[((w * 2 + q) * 64 + l) * 8];
            #pragma unroll
            for (int nt = 0; nt < 10; ++nt)
                acc[q][nt] = __builtin_amdgcn_mfma_f32_16x16x32_bf16(afr, bfr[nt], acc[q][nt], 0, 0, 0);
        }
    }

    #pragma unroll
    for (int q = 0; q < 2; ++q)
        #pragma unroll
        for (int nt = 0; nt < 10; ++nt) {
            int n = n0 + nt * 16 + ln;
            if (n < 300) {
                float bias = b1[n];
                size_t mr = m0 + (w * 2 + q) * 16 + lg * 4;
                #pragma unroll
                for (int i = 0; i < 4; ++i)
                    A[(mr + i) * 300 + n] = acc[q][nt][i] + bias;
            }
        }
}

// ---------------------------------------------------------------------------
// K2: recurrence with MFMA. 8 blocks x 512 thr (8 waves). Block owns 16 batches.
// W1h (bf16) in VGPR A-fragments (waves 0-3: 3 M-tiles, 4-7: 2). h exchanged
// via double-buffered LDS B-fragments. ONE raw s_barrier per step (lgkmcnt(0)
// before it); global A-prefetch (2-deep) and delayed packed-h stores stay in
// flight across barriers (no vmcnt(0) drain). Race-free: packed store at time
// tt clobbers f32 bytes of times <= tt only; loads read time t+2 > tt.
// __launch_bounds__(512) (no min-waves) -> 256-VGPR budget, no afrag spill.
// ---------------------------------------------------------------------------
__global__ __launch_bounds__(512) void elman_rec_mfma(
    const float* __restrict__ W1, float* __restrict__ buf,
    float* __restrict__ hfinal)
{
    __shared__ unsigned short hlds[2][10 * 64 * 8];   // 2 x 10KB
    const int tid = threadIdx.x;
    const int w = tid >> 6, l = tid & 63, lg = l >> 4, ln = l & 15;
    const bool w4 = (w < 4);
    const int bb = blockIdx.x * 16 + ln;    // this lane's batch (B/C column)

    int rq[3], ldsidx[3];
    #pragma unroll
    for (int q = 0; q < 3; ++q) {
        int tile = w4 ? (3 * w + q) : (12 + 2 * (w - 4) + q);
        int r = tile * 16 + 4 * lg;
        rq[q] = r;
        ldsidx[q] = ((r >> 5) * 64 + ((r >> 3) & 3) * 16 + ln) * 8 + (r & 7);
    }

    // Load W1h A-fragments into registers (rows >=300 and k>=300 zeroed).
    bf16x8 afrag[3][10];
    #pragma unroll
    for (int q = 0; q < 3; ++q) {
        #pragma unroll
        for (int kt = 0; kt < 10; ++kt) {
            bool qa = (q < 2) || w4;
            int tile = w4 ? (3 * w + q) : (12 + 2 * (w - 4) + q);
            int r = tile * 16 + ln;
            int k0 = kt * 32 + lg * 8;
            uint4 p = load8_cvt(W1 + (size_t)r * 600 + 300 + k0,
                                qa && r < 300, 300 - k0);
            union { uint4 u; bf16x8 s; } cv; cv.u = p;
            afrag[q][kt] = cv.s;
        }
    }

    for (int i = tid; i < 10 * 64 * 8; i += 512) hlds[0][i] = 0;

    // prefetch A(0), A(1)
    f32x4 Acur[3], Anext[3];
    {
        const float* a0 = buf + (size_t)bb * T_ * 300;
        #pragma unroll
        for (int q = 0; q < 3; ++q)
            if ((q < 2) || w4) {
                Acur[q]  = *(const f32x4*)(a0 + rq[q]);
                Anext[q] = *(const f32x4*)(a0 + 300 + rq[q]);
            }
    }
    uint2 hp[3];
    __syncthreads();

    for (int t = 0; t < T_; ++t) {
        const int cur = t & 1, nxt = cur ^ 1;

        // issue prefetch for t+2 (clamped re-read of row 1023 at the tail:
        // safe, stores so far clobber only times <= t-1 < 1023)
        f32x4 Afar[3];
        {
            const int tpf = (t + 2 < T_) ? (t + 2) : (T_ - 1);
            const float* ar = buf + ((size_t)bb * T_ + tpf) * 300;
            #pragma unroll
            for (int q = 0; q < 3; ++q)
                if ((q < 2) || w4) Afar[q] = *(const f32x4*)(ar + rq[q]);
        }

        // delayed packed-h global store for step t-1
        if (t > 0) {
            int tt = t - 1;
            char* pb = (char*)buf;
            size_t gb = (size_t)(bb * 16 + (tt >> 6)) * 76800 + (size_t)(tt & 63) * 600;
            #pragma unroll
            for (int q = 0; q < 3; ++q)
                if (((q < 2) || w4) && rq[q] < 300)
                    *(uint2*)(pb + gb + rq[q] * 2) = hp[q];
        }

        // MFMA: acc = W1h (A-frags) x h (B-frags from LDS)
        f32x4 acc[3];
        #pragma unroll
        for (int q = 0; q < 3; ++q) acc[q] = (f32x4){0.f,0.f,0.f,0.f};
        #pragma unroll
        for (int kt = 0; kt < 10; ++kt) {
            bf16x8 bfr = *(const bf16x8*)&hlds[cur][(kt * 64 + l) * 8];
            acc[0] = __builtin_amdgcn_mfma_f32_16x16x32_bf16(afrag[0][kt], bfr, acc[0], 0, 0, 0);
            acc[1] = __builtin_amdgcn_mfma_f32_16x16x32_bf16(afrag[1][kt], bfr, acc[1], 0, 0, 0);
            if (w4)
                acc[2] = __builtin_amdgcn_mfma_f32_16x16x32_bf16(afrag[2][kt], bfr, acc[2], 0, 0, 0);
        }

        // sigmoid + pack + LDS write (next buffer) + hfinal at t=1023
        #pragma unroll
        for (int q = 0; q < 3; ++q) {
            if (q == 2 && !w4) continue;
            f32x4 hv;
            #pragma unroll
            for (int i = 0; i < 4; ++i) {
                float z = acc[q][i] + Acur[q][i];
                hv[i] = 1.f / (1.f + __expf(-z));
            }
            if (rq[q] >= 300) hv = (f32x4){0.f,0.f,0.f,0.f};
            uint2 p;
            p.x = (unsigned)f2bf(hv[0]) | ((unsigned)f2bf(hv[1]) << 16);
            p.y = (unsigned)f2bf(hv[2]) | ((unsigned)f2bf(hv[3]) << 16);
            hp[q] = p;
            *(uint2*)&hlds[nxt][ldsidx[q]] = p;
            if (t == T_ - 1 && rq[q] < 300)
                *(f32x4*)(hfinal + bb * 300 + rq[q]) = hv;
        }

        // rotate prefetch ring
        #pragma unroll
        for (int q = 0; q < 3; ++q)
            if ((q < 2) || w4) { Acur[q] = Anext[q]; Anext[q] = Afar[q]; }

        // publish h(t): LDS writes done -> barrier. Global ops NOT drained.
        asm volatile("s_waitcnt lgkmcnt(0)" ::: "memory");
        __builtin_amdgcn_s_barrier();
        asm volatile("" ::: "memory");
    }

    // tail: packed store for t=1023
    {
        int tt = T_ - 1;
        char* pb = (char*)buf;
        size_t gb = (size_t)(bb * 16 + (tt >> 6)) * 76800 + (size_t)(tt & 63) * 600;
        #pragma unroll
        for (int q = 0; q < 3; ++q)
            if (((q < 2) || w4) && rq[q] < 300)
                *(uint2*)(pb + gb + rq[q] * 2) = hp[q];
    }
}

// ---------------------------------------------------------------------------
// K3: out[m][n] = sum_k h[m][k]*W2[n][k] + b2[n], in place over packed-h buf.
// One block per 64-row chunk (grid 2048); block computes ALL 300 columns, so
// packed bytes a block reads are written only by that block after its final
// global read. 256 thr (4 waves): wave w owns M-tile w x 19 N-tiles.
// ---------------------------------------------------------------------------
__global__ __launch_bounds__(256) void gemm_out(
    float* __restrict__ buf, const float* __restrict__ W2,
    const float* __restrict__ b2)
{
    __shared__ unsigned short alds[4 * 64 * 8];    // 4 KB packed-h tile
    __shared__ unsigned short blds[19 * 64 * 8];   // 19 KB W2 tile
    const int tid = threadIdx.x;
    const int w = tid >> 6, l = tid & 63, lg = l >> 4, ln = l & 15;
    const size_t chunk = blockIdx.x;               // 64-row chunk
    const char* pbase = (const char*)buf + chunk * 76800;

    f32x4 acc[19];
    #pragma unroll
    for (int nt = 0; nt < 19; ++nt) acc[nt] = (f32x4){0.f,0.f,0.f,0.f};

    for (int kt = 0; kt < 10; ++kt) {
        const int kc = kt * 32;
        __syncthreads();
        // stage packed bf16 h tile: 64 rows x 32 k, one entry per thread
        {
            int row = tid >> 2, kh = tid & 3;
            int k0 = kc + kh * 8;
            const char* p = pbase + row * 600;
            uint2 lo = make_uint2(0u, 0u), hi = make_uint2(0u, 0u);
            int krem = 300 - k0;
            if (krem >= 8)      { lo = *(const uint2*)(p + k0 * 2); hi = *(const uint2*)(p + k0 * 2 + 8); }
            else if (krem >= 4) { lo = *(const uint2*)(p + k0 * 2); }
            uint4 pk; pk.x = lo.x; pk.y = lo.y; pk.z = hi.x; pk.w = hi.y;
            *(uint4*)&alds[(((row >> 4) * 64) + kh * 16 + (row & 15)) * 8] = pk;
        }
        // stage W2 tile: 304 n-rows x 32 k
        #pragma unroll
        for (int rep = 0; rep < 5; ++rep) {
            int e = tid + rep * 256;
            if (e < 1216) {
                int nn = e >> 2, kh = e & 3;
                int k0 = kc + kh * 8;
                uint4 p = load8_cvt(W2 + (size_t)nn * 300 + k0, nn < 300, 300 - k0);
                *(uint4*)&blds[(((nn >> 4) * 64) + kh * 16 + (nn & 15)) * 8] = p;
            }
        }
        __syncthreads();
        bf16x8 afr = *(const bf16x8*)&alds[(w * 64 + l) * 8];
        #pragma unroll
        for (int nt = 0; nt < 19; ++nt) {
            bf16x8 bfr = *(const bf16x8*)&blds[(nt * 64 + l) * 8];
            acc[nt] = __builtin_amdgcn_mfma_f32_16x16x32_bf16(afr, bfr, acc[nt], 0, 0, 0);
        }
    }

    // overwrite chunk with f32 outputs
    float* frow = buf + chunk * 19200;             // 64 rows * 300 cols
    #pragma unroll
    for (int nt = 0; nt < 19; ++nt) {
        int n = nt * 16 + ln;
        if (n < 300) {
            float bias = b2[n];
            int mr = w * 16 + lg * 4;
            #pragma unroll
            for (int i = 0; i < 4; ++i)
                frow[(mr + i) * 300 + n] = acc[nt][i] + bias;
        }
    }
}

// ---------------------------------------------------------------------------
extern "C" void kernel_launch(void* const* d_in, const int* in_sizes, int n_in,
                              void* d_out, int out_size, void* d_ws, size_t ws_size,
                              hipStream_t stream)
{
    const float* x  = (const float*)d_in[0];
    const float* W1 = (const float*)d_in[1];
    const float* b1 = (const float*)d_in[2];
    const float* W2 = (const float*)d_in[3];
    const float* b2 = (const float*)d_in[4];

    float* out    = (float*)d_out;
    float* hfinal = out + (size_t)HB;

    gemm_in<<<dim3(1024, 2), 256, 0, stream>>>(x, W1, b1, out);
    elman_rec_mfma<<<8, 512, 0, stream>>>(W1, out, hfinal);
    gemm_out<<<2048, 256, 0, stream>>>(out, W2, b2);
}